// Round 1
// baseline (1459.862 us; speedup 1.0000x reference)
//
#include <hip/hip_runtime.h>
#include <hip/hip_bf16.h>

typedef unsigned short ushort_t;
using short8 = __attribute__((ext_vector_type(8))) short;
using f32x4  = __attribute__((ext_vector_type(4))) float;

#define DEVI __device__ __forceinline__

DEVI ushort_t f2bf(float f) {
    union { float f; unsigned u; } c; c.f = f;
    unsigned u = c.u;
    return (ushort_t)((u + 0x7FFF + ((u >> 16) & 1)) >> 16);
}

DEVI f32x4 mfma16(short8 a, short8 b, f32x4 c) {
    return __builtin_amdgcn_mfma_f32_16x16x32_bf16(a, b, c, 0, 0, 0);
}

DEVI void gld16(const void* g, void* l) {
    __builtin_amdgcn_global_load_lds(
        (const __attribute__((address_space(1))) unsigned int*)g,
        (__attribute__((address_space(3))) unsigned int*)l, 16, 0, 0);
}

// ---------------- constants ----------------
#define Bsz 16
#define Ntok 1024
#define Cdim 1152
#define Hn 16
#define Dh 72
#define Dp 96
#define INNER 4608
#define Mrows (Bsz * Ntok)   // 16384

// workspace offsets (bytes)
#define OFF_QKV_WT  ((size_t)0)
#define OFF_PROJ_WT ((size_t)7962624)
#define OFF_FC1_WT  ((size_t)10616832)
#define OFF_FC2_WT  ((size_t)21233664)
#define OFF_H       ((size_t)31850496)
#define OFF_ATT     ((size_t)69599232)
#define OFF_Q       ((size_t)107347968)
#define OFF_K       ((size_t)157679616)
#define OFF_VT      ((size_t)208011264)
// hidden (16384x4608 bf16 = 150994944 B) aliases OFF_Q..OFF_VT end (dead by then)
#define OFF_HIDDEN  OFF_Q

// ---------------- weight transpose + cast: W[K][N] f32 -> Wt[N][K] bf16 ----------------
__global__ __launch_bounds__(256) void transpose_cast(
    const float* __restrict__ W, ushort_t* __restrict__ Wt, int K, int N)
{
    __shared__ float t[64][65];
    const int n0 = blockIdx.x * 64;
    const int k0 = blockIdx.y * 64;
    #pragma unroll
    for (int j = 0; j < 4; ++j) {
        int idx = threadIdx.x + j * 256;
        int r = idx >> 4;       // k row 0..63
        int c4 = idx & 15;      // n group of 4
        float4 v = *(const float4*)&W[(size_t)(k0 + r) * N + n0 + c4 * 4];
        t[r][c4 * 4 + 0] = v.x; t[r][c4 * 4 + 1] = v.y;
        t[r][c4 * 4 + 2] = v.z; t[r][c4 * 4 + 3] = v.w;
    }
    __syncthreads();
    #pragma unroll
    for (int j = 0; j < 4; ++j) {
        int idx = threadIdx.x + j * 256;
        int rn = idx >> 4;      // n row 0..63
        int c4 = idx & 15;      // k group of 4
        ushort4 o;
        o.x = f2bf(t[c4 * 4 + 0][rn]);
        o.y = f2bf(t[c4 * 4 + 1][rn]);
        o.z = f2bf(t[c4 * 4 + 2][rn]);
        o.w = f2bf(t[c4 * 4 + 3][rn]);
        *(ushort4*)&Wt[(size_t)(n0 + rn) * K + k0 + c4 * 4] = o;
    }
}

// ---------------- LayerNorm: f32 row(1152) -> bf16 ----------------
__global__ __launch_bounds__(256) void ln_kernel(
    const float* __restrict__ x, const float* __restrict__ g,
    const float* __restrict__ b, ushort_t* __restrict__ out)
{
    const int row = blockIdx.x;
    const int tid = threadIdx.x;
    const int lane = tid & 63, wid = tid >> 6;
    const float* xr = x + (size_t)row * Cdim;

    float4 v0 = ((const float4*)xr)[tid];
    float4 v1 = {0, 0, 0, 0};
    if (tid < 32) v1 = ((const float4*)xr)[256 + tid];
    float s  = v0.x + v0.y + v0.z + v0.w + v1.x + v1.y + v1.z + v1.w;
    float s2 = v0.x*v0.x + v0.y*v0.y + v0.z*v0.z + v0.w*v0.w
             + v1.x*v1.x + v1.y*v1.y + v1.z*v1.z + v1.w*v1.w;
    #pragma unroll
    for (int off = 32; off >= 1; off >>= 1) {
        s  += __shfl_xor(s, off);
        s2 += __shfl_xor(s2, off);
    }
    __shared__ float red[8];
    if (lane == 0) { red[wid] = s; red[4 + wid] = s2; }
    __syncthreads();
    s  = red[0] + red[1] + red[2] + red[3];
    s2 = red[4] + red[5] + red[6] + red[7];
    const float mu = s * (1.0f / Cdim);
    const float var = s2 * (1.0f / Cdim) - mu * mu;
    const float rs = rsqrtf(var + 1e-6f);

    ushort_t* orow = out + (size_t)row * Cdim;
    {
        float4 g4 = ((const float4*)g)[tid];
        float4 b4 = ((const float4*)b)[tid];
        ushort4 o;
        o.x = f2bf((v0.x - mu) * rs * g4.x + b4.x);
        o.y = f2bf((v0.y - mu) * rs * g4.y + b4.y);
        o.z = f2bf((v0.z - mu) * rs * g4.z + b4.z);
        o.w = f2bf((v0.w - mu) * rs * g4.w + b4.w);
        ((ushort4*)orow)[tid] = o;
    }
    if (tid < 32) {
        float4 g4 = ((const float4*)g)[256 + tid];
        float4 b4 = ((const float4*)b)[256 + tid];
        ushort4 o;
        o.x = f2bf((v1.x - mu) * rs * g4.x + b4.x);
        o.y = f2bf((v1.y - mu) * rs * g4.y + b4.y);
        o.z = f2bf((v1.z - mu) * rs * g4.z + b4.z);
        o.w = f2bf((v1.w - mu) * rs * g4.w + b4.w);
        ((ushort4*)orow)[256 + tid] = o;
    }
}

// ---------------- GEMM: C[M,N] = A[M,K](bf16) @ Bt[N,K]^T(bf16), epilogues ----------------
enum { EPI_QKV = 0, EPI_PROJ = 1, EPI_FC1 = 2, EPI_FC2 = 3 };

template<int EPI, int N, int K>
__global__ __launch_bounds__(256) void gemm_bt(
    const ushort_t* __restrict__ A, const ushort_t* __restrict__ Bt,
    const float* __restrict__ bias, const float* __restrict__ resid,
    float* __restrict__ outf, ushort_t* __restrict__ outb,
    ushort_t* __restrict__ outq, ushort_t* __restrict__ outk, ushort_t* __restrict__ outv)
{
    __shared__ ushort_t As[128 * 32];
    __shared__ ushort_t Bs[128 * 32];
    const int tid = threadIdx.x;
    const int lane = tid & 63, wid = tid >> 6;
    const int m0 = blockIdx.y * 128;
    const int n0 = blockIdx.x * 128;
    const int fr = lane & 15, fq = lane >> 4;

    f32x4 acc[4][4] = {};

    const int srow = lane >> 2;          // 0..15 within 16-row chunk
    const int scol = (lane & 3) * 8;     // k element offset within 32
    const ushort_t* Ag = A + (size_t)m0 * K;
    const ushort_t* Bg = Bt + (size_t)n0 * K;

    for (int kk = 0; kk < K; kk += 32) {
        #pragma unroll
        for (int j = 0; j < 2; ++j) {
            const int crow = wid * 32 + j * 16;          // chunk base row
            gld16(Ag + (size_t)(crow + srow) * K + kk + scol, &As[crow * 32]);
            gld16(Bg + (size_t)(crow + srow) * K + kk + scol, &Bs[crow * 32]);
        }
        __syncthreads();
        short8 af[4], bfr[4];
        #pragma unroll
        for (int mi = 0; mi < 4; ++mi)
            af[mi] = *(const short8*)&As[((wid >> 1) * 64 + mi * 16 + fr) * 32 + fq * 8];
        #pragma unroll
        for (int ni = 0; ni < 4; ++ni)
            bfr[ni] = *(const short8*)&Bs[((wid & 1) * 64 + ni * 16 + fr) * 32 + fq * 8];
        #pragma unroll
        for (int mi = 0; mi < 4; ++mi)
            #pragma unroll
            for (int ni = 0; ni < 4; ++ni)
                acc[mi][ni] = mfma16(af[mi], bfr[ni], acc[mi][ni]);
        __syncthreads();
    }

    #pragma unroll
    for (int mi = 0; mi < 4; ++mi) {
        #pragma unroll
        for (int ni = 0; ni < 4; ++ni) {
            const int col = n0 + (wid & 1) * 64 + ni * 16 + fr;
            const int rbase = m0 + (wid >> 1) * 64 + mi * 16 + fq * 4;
            #pragma unroll
            for (int i = 0; i < 4; ++i) {
                const int r = rbase + i;
                float v = acc[mi][ni][i];
                if (EPI == EPI_QKV) {
                    v += bias[col];
                    const int which = col / Cdim;
                    const int rc = col % Cdim;
                    const int h = rc / Dh, d = rc % Dh;
                    const int b = r >> 10, n = r & 1023;
                    const size_t head = (size_t)(b * Hn + h);
                    if (which == 0)      outq[(head * Ntok + n) * Dp + d] = f2bf(v);
                    else if (which == 1) outk[(head * Ntok + n) * Dp + d] = f2bf(v);
                    else                 outv[(head * Dp + d) * Ntok + n] = f2bf(v);
                } else if (EPI == EPI_PROJ) {
                    v += bias[col] + resid[(size_t)r * N + col];
                    outf[(size_t)r * N + col] = v;
                } else if (EPI == EPI_FC1) {
                    v += bias[col];
                    v = 0.5f * v * (1.0f + erff(v * 0.70710678118f));
                    outb[(size_t)r * N + col] = f2bf(v);
                } else { // EPI_FC2
                    v += bias[col] + outf[(size_t)r * N + col];
                    outf[(size_t)r * N + col] = v;
                }
            }
        }
    }
}

// ---------------- flash attention: q,k (bh,n,96) bf16; vt (bh,96,n); out (b,n,1152) bf16 ----
__global__ __launch_bounds__(256) void attn_kernel(
    const ushort_t* __restrict__ q, const ushort_t* __restrict__ k,
    const ushort_t* __restrict__ vt, ushort_t* __restrict__ out)
{
    const int tid = threadIdx.x;
    const int lane = tid & 63, wid = tid >> 6;
    const int bh = blockIdx.y;
    const int q0 = blockIdx.x * 64 + wid * 16;
    const int fr = lane & 15, fq = lane >> 4;
    const ushort_t* qh = q  + (size_t)bh * Ntok * Dp;
    const ushort_t* kh = k  + (size_t)bh * Ntok * Dp;
    const ushort_t* vh = vt + (size_t)bh * Dp * Ntok;

    short8 aq[3];
    #pragma unroll
    for (int ks = 0; ks < 3; ++ks)
        aq[ks] = *(const short8*)&qh[(size_t)(q0 + fr) * Dp + ks * 32 + fq * 8];

    f32x4 o[5] = {};
    float mrun[4], lrun[4];
    #pragma unroll
    for (int i = 0; i < 4; ++i) { mrun[i] = -1e30f; lrun[i] = 0.0f; }

    __shared__ ushort_t plds[4][16][32];
    const float scale = 0.117851130f;   // 72^-0.5

    for (int kv = 0; kv < Ntok; kv += 32) {
        f32x4 s0 = {}, s1 = {};
        #pragma unroll
        for (int ks = 0; ks < 3; ++ks) {
            short8 b0 = *(const short8*)&kh[(size_t)(kv + fr) * Dp + ks * 32 + fq * 8];
            short8 b1 = *(const short8*)&kh[(size_t)(kv + 16 + fr) * Dp + ks * 32 + fq * 8];
            s0 = mfma16(aq[ks], b0, s0);
            s1 = mfma16(aq[ks], b1, s1);
        }
        float p0[4], p1[4], corr[4];
        #pragma unroll
        for (int i = 0; i < 4; ++i) {
            float a = s0[i] * scale, c = s1[i] * scale;
            float mx = fmaxf(a, c);
            mx = fmaxf(mx, __shfl_xor(mx, 1));
            mx = fmaxf(mx, __shfl_xor(mx, 2));
            mx = fmaxf(mx, __shfl_xor(mx, 4));
            mx = fmaxf(mx, __shfl_xor(mx, 8));
            const float mnew = fmaxf(mrun[i], mx);
            const float f = __expf(mrun[i] - mnew);
            mrun[i] = mnew;
            p0[i] = __expf(a - mnew);
            p1[i] = __expf(c - mnew);
            float ps = p0[i] + p1[i];
            ps += __shfl_xor(ps, 1);
            ps += __shfl_xor(ps, 2);
            ps += __shfl_xor(ps, 4);
            ps += __shfl_xor(ps, 8);
            lrun[i] = lrun[i] * f + ps;
            corr[i] = f;
        }
        #pragma unroll
        for (int dt = 0; dt < 5; ++dt)
            #pragma unroll
            for (int i = 0; i < 4; ++i) o[dt][i] *= corr[i];
        #pragma unroll
        for (int i = 0; i < 4; ++i) {
            plds[wid][fq * 4 + i][fr]      = f2bf(p0[i]);
            plds[wid][fq * 4 + i][16 + fr] = f2bf(p1[i]);
        }
        __syncthreads();
        short8 pa = *(const short8*)&plds[wid][fr][fq * 8];
        #pragma unroll
        for (int dt = 0; dt < 5; ++dt) {
            short8 bv = *(const short8*)&vh[(size_t)(dt * 16 + fr) * Ntok + kv + fq * 8];
            o[dt] = mfma16(pa, bv, o[dt]);
        }
        __syncthreads();
    }

    float inv[4];
    #pragma unroll
    for (int i = 0; i < 4; ++i) inv[i] = 1.0f / lrun[i];
    const int b = bh >> 4, h = bh & 15;
    #pragma unroll
    for (int dt = 0; dt < 5; ++dt) {
        const int d = dt * 16 + fr;
        if (d < Dh) {
            #pragma unroll
            for (int i = 0; i < 4; ++i) {
                const size_t idx = ((size_t)(b * Ntok) + q0 + fq * 4 + i) * Cdim + h * Dh + d;
                out[idx] = f2bf(o[dt][i] * inv[i]);
            }
        }
    }
}

// ---------------- launch ----------------
extern "C" void kernel_launch(void* const* d_in, const int* in_sizes, int n_in,
                              void* d_out, int out_size, void* d_ws, size_t ws_size,
                              hipStream_t stream) {
    const float* x      = (const float*)d_in[0];
    const float* ln1_g  = (const float*)d_in[1];
    const float* ln1_b  = (const float*)d_in[2];
    const float* qkv_w  = (const float*)d_in[3];
    const float* qkv_b  = (const float*)d_in[4];
    const float* proj_w = (const float*)d_in[5];
    const float* proj_b = (const float*)d_in[6];
    const float* ln2_g  = (const float*)d_in[7];
    const float* ln2_b  = (const float*)d_in[8];
    const float* fc1_w  = (const float*)d_in[9];
    const float* fc1_b  = (const float*)d_in[10];
    const float* fc2_w  = (const float*)d_in[11];
    const float* fc2_b  = (const float*)d_in[12];

    char* ws = (char*)d_ws;
    ushort_t* qkv_wT  = (ushort_t*)(ws + OFF_QKV_WT);
    ushort_t* proj_wT = (ushort_t*)(ws + OFF_PROJ_WT);
    ushort_t* fc1_wT  = (ushort_t*)(ws + OFF_FC1_WT);
    ushort_t* fc2_wT  = (ushort_t*)(ws + OFF_FC2_WT);
    ushort_t* hbuf    = (ushort_t*)(ws + OFF_H);
    ushort_t* attnout = (ushort_t*)(ws + OFF_ATT);
    ushort_t* qb      = (ushort_t*)(ws + OFF_Q);
    ushort_t* kb      = (ushort_t*)(ws + OFF_K);
    ushort_t* vtb     = (ushort_t*)(ws + OFF_VT);
    ushort_t* hidden  = (ushort_t*)(ws + OFF_HIDDEN);
    float* out = (float*)d_out;

    // zero q/k/vt (covers the D=72..95 padding the MFMA K-loop reads)
    hipMemsetAsync(ws + OFF_Q, 0, (size_t)3 * 50331648, stream);

    transpose_cast<<<dim3(3 * Cdim / 64, Cdim / 64), 256, 0, stream>>>(qkv_w, qkv_wT, Cdim, 3 * Cdim);
    transpose_cast<<<dim3(Cdim / 64, Cdim / 64), 256, 0, stream>>>(proj_w, proj_wT, Cdim, Cdim);
    transpose_cast<<<dim3(INNER / 64, Cdim / 64), 256, 0, stream>>>(fc1_w, fc1_wT, Cdim, INNER);
    transpose_cast<<<dim3(Cdim / 64, INNER / 64), 256, 0, stream>>>(fc2_w, fc2_wT, INNER, Cdim);

    ln_kernel<<<Mrows, 256, 0, stream>>>(x, ln1_g, ln1_b, hbuf);

    gemm_bt<EPI_QKV, 3 * Cdim, Cdim><<<dim3(27, 128), 256, 0, stream>>>(
        hbuf, qkv_wT, qkv_b, nullptr, nullptr, nullptr, qb, kb, vtb);

    attn_kernel<<<dim3(Ntok / 64, Bsz * Hn), 256, 0, stream>>>(qb, kb, vtb, attnout);

    gemm_bt<EPI_PROJ, Cdim, Cdim><<<dim3(9, 128), 256, 0, stream>>>(
        attnout, proj_wT, proj_b, x, out, nullptr, nullptr, nullptr, nullptr);

    ln_kernel<<<Mrows, 256, 0, stream>>>(out, ln2_g, ln2_b, hbuf);

    gemm_bt<EPI_FC1, INNER, Cdim><<<dim3(36, 128), 256, 0, stream>>>(
        hbuf, fc1_wT, fc1_b, nullptr, nullptr, hidden, nullptr, nullptr, nullptr);

    gemm_bt<EPI_FC2, Cdim, INNER><<<dim3(9, 128), 256, 0, stream>>>(
        hidden, fc2_wT, fc2_b, nullptr, out, nullptr, nullptr, nullptr, nullptr);
}